// Round 6
// baseline (780.109 us; speedup 1.0000x reference)
//
#include <hip/hip_runtime.h>
#include <math.h>

#define QN 20000
#define PN 80000   // QN*4
#define CN 128
#define NVIEW 6

typedef __attribute__((ext_vector_type(8))) short bf16x8;
typedef __attribute__((ext_vector_type(4))) float f32x4;
typedef unsigned short us;

__device__ __forceinline__ us f2bf(float f) {
  unsigned u = __float_as_uint(f);
  return (us)((u + 0x7fffu + ((u >> 16) & 1u)) >> 16);
}
__device__ __forceinline__ float bf2f(us h) {
  return __uint_as_float(((unsigned)h) << 16);
}

__device__ __forceinline__ void gload16(const void* g, void* l) {
  __builtin_amdgcn_global_load_lds(
      (const __attribute__((address_space(1))) void*)g,
      (__attribute__((address_space(3))) void*)l, 16, 0, 0);
}

// ---------------- weight transpose+split: W[K][N] f32 -> T[2][N][Kp] bf16 ----
__global__ __launch_bounds__(256) void wsplit_kernel(const float* __restrict__ W,
                                                     us* __restrict__ Th,
                                                     int K, int N, int Kp) {
  __shared__ float t[32][33];
  us* Tl = Th + (size_t)N * Kp;
  const int n0 = blockIdx.x * 32, k0 = blockIdx.y * 32;
  const int tx = threadIdx.x & 31, ty = threadIdx.x >> 5;  // ty 0..7
  #pragma unroll
  for (int j = 0; j < 4; ++j) {
    int k = k0 + ty + j * 8;
    t[ty + j * 8][tx] = (k < K) ? W[(size_t)k * N + n0 + tx] : 0.f;
  }
  __syncthreads();
  #pragma unroll
  for (int j = 0; j < 4; ++j) {
    int n = n0 + ty + j * 8;
    int k = k0 + tx;
    float v = t[tx][ty + j * 8];
    us h = f2bf(v);
    Th[(size_t)n * Kp + k] = h;
    Tl[(size_t)n * Kp + k] = f2bf(v - bf2f(h));
  }
}

// ---------------- PE input features -> split bf16 planes [2][PN][64] ---------
__global__ __launch_bounds__(256) void pe_in_kernel(const float* __restrict__ rp,
                                                    us* __restrict__ Ph) {
  int idx = blockIdx.x * 256 + threadIdx.x;
  if (idx >= PN * 64) return;
  us* Pl = Ph + (size_t)PN * 64;
  int p = idx >> 6, k = idx & 63;
  float val = 0.f;
  if (k < 60) {
    int q = p >> 2, z = p & 3;
    int d = k / 20, r = k - d * 20;
    int j = (r >= 10) ? (r - 10) : r;
    float pos = rp[((size_t)z * QN + q) * 3 + d];
    float ang = pos * ((float)(1 << j) * 3.14159265358979323846f);
    val = (r >= 10) ? cosf(ang) : sinf(ang);
  }
  us h = f2bf(val);
  Ph[idx] = h;
  Pl[idx] = f2bf(val - bf2f(h));
}

// ---------------- split-bf16 3-term GEMM via augmented-K single stream -------
// C = (Ah+Al)[M][K] @ (Bh+Bl)^T[N][K] + bias. Tiles t in [0, 3K/64):
//   t < K/64: ah*bh | t < 2K/64: al*bh | else: ah*bl   (al*bl ~2^-17 dropped)
// 128x128 tile, BK=64, 256 thr (2x2 waves, 64x64/wave). Two-phase pipeline:
// issue STAGE(t+1) BEFORE COMPUTE(t), one __syncthreads per tile (full drain
// -- no counted-vmcnt ordering assumptions; WAR safe via previous barrier).
// OUT=0: f32 C. OUT=1: split bf16 planes (Cl = Ch + M*N).
template <bool RELU, int OUT>
__global__ __launch_bounds__(256, 2) void gemm_aug(const us* __restrict__ Ah,
                                                   const us* __restrict__ Bh,
                                                   const float* __restrict__ bias,
                                                   float* __restrict__ Cf,
                                                   us* __restrict__ Ch,
                                                   int M, int N, int K) {
  __shared__ short smA[2][8192];  // [buf][128 rows][64 k] bf16
  __shared__ short smB[2][8192];
  const us* __restrict__ Al = Ah + (size_t)M * K;
  const us* __restrict__ Bl = Bh + (size_t)N * K;
  const int tid = threadIdx.x;
  const int wave = tid >> 6, lane = tid & 63;
  const int wr = wave >> 1, wc = wave & 1;
  const int bm = blockIdx.y * 128, bn = blockIdx.x * 128;
  const int g = lane >> 4, r16 = lane & 15;
  const int n1 = K >> 6;
  const int nt = 3 * n1;

  f32x4 acc[4][4];
  #pragma unroll
  for (int i = 0; i < 4; ++i)
    #pragma unroll
    for (int j = 0; j < 4; ++j) acc[i][j] = {0.f, 0.f, 0.f, 0.f};

  // stage one K-tile (A 128x64 + B 128x64) into buf
  auto STAGE = [&](int buf, int t) {
    const us* Ap = (t < n1) ? Ah : (t < 2 * n1) ? Al : Ah;
    const us* Bp = (t < 2 * n1) ? Bh : Bl;
    int kof = ((t < n1) ? t : (t < 2 * n1) ? (t - n1) : (t - 2 * n1)) << 6;
    #pragma unroll
    for (int i = 0; i < 4; ++i) {
      int ii = wave * 4 + i;            // 0..15
      int row = ii * 8 + (lane >> 3);   // 0..127
      int slot = (lane & 7) ^ (row & 7);
      int gcol = kof + slot * 8;
      int so = ii * 512;                // shorts: 1KB per wave-instruction
      int ra = bm + row; if (ra >= M) ra = M - 1;
      gload16(Ap + (size_t)ra * K + gcol, &smA[buf][so]);
      gload16(Bp + (size_t)(bn + row) * K + gcol, &smB[buf][so]);
    }
  };

  auto COMPUTE = [&](int buf) {
    #pragma unroll
    for (int kk = 0; kk < 2; ++kk) {
      bf16x8 a[4], b[4];
      #pragma unroll
      for (int mi = 0; mi < 4; ++mi) {
        int row = wr * 64 + mi * 16 + r16;
        int idx = row * 64 + (((kk * 4 + g) ^ (row & 7)) * 8);
        a[mi] = *(const bf16x8*)&smA[buf][idx];
      }
      #pragma unroll
      for (int ni = 0; ni < 4; ++ni) {
        int row = wc * 64 + ni * 16 + r16;
        int idx = row * 64 + (((kk * 4 + g) ^ (row & 7)) * 8);
        b[ni] = *(const bf16x8*)&smB[buf][idx];
      }
      #pragma unroll
      for (int mi = 0; mi < 4; ++mi)
        #pragma unroll
        for (int ni = 0; ni < 4; ++ni)
          acc[mi][ni] = __builtin_amdgcn_mfma_f32_16x16x32_bf16(a[mi], b[ni], acc[mi][ni], 0, 0, 0);
    }
  };

  // prologue: tile 0 staged and drained
  STAGE(0, 0);
  __syncthreads();                 // vmcnt(0)+lgkmcnt(0)+barrier

  for (int t = 0; t < nt; ++t) {
    if (t + 1 < nt) STAGE((t + 1) & 1, t + 1);  // prefetch next (issue only)
    COMPUTE(t & 1);                             // 32 MFMA overlap the loads
    __syncthreads();               // drain prefetch + WAR fence, once per tile
  }

  // epilogue: D row = (lane>>4)*4 + r, col = lane&15 within each 16x16 frag
  us* Cl = Ch + (size_t)M * N;
  #pragma unroll
  for (int mi = 0; mi < 4; ++mi) {
    int gr0 = bm + wr * 64 + mi * 16 + (lane >> 4) * 4;
    #pragma unroll
    for (int ni = 0; ni < 4; ++ni) {
      int gc = bn + wc * 64 + ni * 16 + r16;
      float bv = bias[gc];
      #pragma unroll
      for (int r = 0; r < 4; ++r) {
        int row = gr0 + r;
        if (row >= M) continue;
        float v = acc[mi][ni][r] + bv;
        if (RELU) v = fmaxf(v, 0.f);
        if (OUT == 0) {
          Cf[(size_t)row * N + gc] = v;
        } else {
          us h = f2bf(v);
          Ch[(size_t)row * N + gc] = h;
          Cl[(size_t)row * N + gc] = f2bf(v - bf2f(h));
        }
      }
    }
  }
}

// ---------------- fused softmax + projection + bilinear sample --------------
// one wave per point; lane handles channels [2*lane, 2*lane+2) as float2.
__global__ __launch_bounds__(256) void sample_kernel(
    const float* __restrict__ f0, const float* __restrict__ f1,
    const float* __restrict__ f2, const float* __restrict__ f3,
    const float* __restrict__ rp, const float* __restrict__ l2i,
    const float* __restrict__ wtw, const float* __restrict__ wtb,
    const float* __restrict__ posE, us* __restrict__ X0h) {
  __shared__ float sl2i[96];
  __shared__ float swtT[512];  // transposed [4][128]
  __shared__ float sb[4];
  const int tid = threadIdx.x;
  if (tid < 96) sl2i[tid] = l2i[tid];
  // FIX r5->r6: blockDim=256, must grid-stride to cover all 512 elements
  // (previous `if (tid < 512)` left channels 64..127 uninitialized -> 3e-2 err)
  for (int i = tid; i < 512; i += 256) swtT[(i & 3) * 128 + (i >> 2)] = wtw[i];
  if (tid < 4) sb[tid] = wtb[tid];
  __syncthreads();

  us* X0l = X0h + (size_t)QN * 512;
  const int wave = tid >> 6, lane = tid & 63;
  const int p = blockIdx.x * 4 + wave;
  const int q = p >> 2, z = p & 3;

  const float X  = rp[((size_t)z * QN + q) * 3 + 0] * 100.f - 50.f;
  const float Y  = rp[((size_t)z * QN + q) * 3 + 1] * 100.f - 50.f;
  const float Zc = rp[((size_t)z * QN + q) * 3 + 2] * 8.f - 4.f;

  const int c0 = lane * 2;
  float2 pe = *(const float2*)(posE + (size_t)p * CN + c0);
  const float e0 = pe.x, e1 = pe.y;

  float l0 = e0 * swtT[0 * 128 + c0] + e1 * swtT[0 * 128 + c0 + 1];
  float l1 = e0 * swtT[1 * 128 + c0] + e1 * swtT[1 * 128 + c0 + 1];
  float l2 = e0 * swtT[2 * 128 + c0] + e1 * swtT[2 * 128 + c0 + 1];
  float l3 = e0 * swtT[3 * 128 + c0] + e1 * swtT[3 * 128 + c0 + 1];
  #pragma unroll
  for (int off = 32; off > 0; off >>= 1) {
    l0 += __shfl_xor(l0, off);
    l1 += __shfl_xor(l1, off);
    l2 += __shfl_xor(l2, off);
    l3 += __shfl_xor(l3, off);
  }
  l0 += sb[0]; l1 += sb[1]; l2 += sb[2]; l3 += sb[3];
  float mx = fmaxf(fmaxf(l0, l1), fmaxf(l2, l3));
  float ex0 = __expf(l0 - mx), ex1 = __expf(l1 - mx);
  float ex2 = __expf(l2 - mx), ex3 = __expf(l3 - mx);
  float esr = 1.f / (ex0 + ex1 + ex2 + ex3);
  float sw[4] = {ex0 * esr, ex1 * esr, ex2 * esr, ex3 * esr};

  const int HH[4] = {64, 32, 16, 8};
  const int WW[4] = {176, 88, 44, 22};
  const float* FT[4] = {f0, f1, f2, f3};

  float acc0 = 0.f, acc1 = 0.f;
  for (int n = 0; n < NVIEW; n++) {
    const float* Mx = sl2i + n * 16;
    float cam0 = Mx[0] * X + Mx[1] * Y + Mx[2]  * Zc + Mx[3];
    float cam1 = Mx[4] * X + Mx[5] * Y + Mx[6]  * Zc + Mx[7];
    float cam2 = Mx[8] * X + Mx[9] * Y + Mx[10] * Zc + Mx[11];
    float denom = fmaxf(cam2, 1e-5f);
    float u = cam0 / denom * (1.f / 704.f);
    float v = cam1 / denom * (1.f / 256.f);
    if (!(cam2 > 1e-5f && u > 0.f && u < 1.f && v > 0.f && v < 1.f)) continue;
    #pragma unroll
    for (int l = 0; l < 4; l++) {
      const int Hl = HH[l], Wl = WW[l];
      float pxl = u * (float)Wl - 0.5f;
      float pyl = v * (float)Hl - 0.5f;
      float fx = floorf(pxl), fy = floorf(pyl);
      int x0 = (int)fx, y0 = (int)fy;
      float wx = pxl - fx, wy = pyl - fy;
      const float wxs[2] = {1.f - wx, wx};
      const float wys[2] = {1.f - wy, wy};
      const float* fb = FT[l] + (size_t)n * Hl * Wl * CN;
      #pragma unroll
      for (int cy = 0; cy < 2; cy++) {
        #pragma unroll
        for (int cx = 0; cx < 2; cx++) {
          int xi = x0 + cx, yi = y0 + cy;
          bool inb = (xi >= 0) & (xi < Wl) & (yi >= 0) & (yi < Hl);
          int xc = min(max(xi, 0), Wl - 1);
          int yc = min(max(yi, 0), Hl - 1);
          float wgt = inb ? (wys[cy] * wxs[cx] * sw[l]) : 0.f;
          float2 vv = ((const float2*)(fb + ((size_t)yc * Wl + xc) * CN))[lane];
          acc0 = fmaf(wgt, vv.x, acc0);
          acc1 = fmaf(wgt, vv.y, acc1);
        }
      }
    }
  }
  float v0 = acc0 + e0;
  float v1 = acc1 + e1;
  size_t base = (size_t)p * CN + c0;  // = q*512 + z*128 + c0
  us h0 = f2bf(v0), h1 = f2bf(v1);
  ushort2 hi = {h0, h1};
  ushort2 lo = {f2bf(v0 - bf2f(h0)), f2bf(v1 - bf2f(h1))};
  *(ushort2*)&X0h[base] = hi;
  *(ushort2*)&X0l[base] = lo;
}

extern "C" void kernel_launch(void* const* d_in, const int* in_sizes, int n_in,
                              void* d_out, int out_size, void* d_ws, size_t ws_size,
                              hipStream_t stream) {
  const float* feat0 = (const float*)d_in[0];
  const float* feat1 = (const float*)d_in[1];
  const float* feat2 = (const float*)d_in[2];
  const float* feat3 = (const float*)d_in[3];
  const float* rp    = (const float*)d_in[4];
  const float* l2i   = (const float*)d_in[5];
  const float* pe_w1 = (const float*)d_in[6];
  const float* pe_b1 = (const float*)d_in[7];
  const float* pe_w2 = (const float*)d_in[8];
  const float* pe_b2 = (const float*)d_in[9];
  const float* wt_w  = (const float*)d_in[10];
  const float* wt_b  = (const float*)d_in[11];
  const float* hm_w1 = (const float*)d_in[12];
  const float* hm_b1 = (const float*)d_in[13];
  const float* hm_w2 = (const float*)d_in[14];
  const float* hm_b2 = (const float*)d_in[15];
  const float* hm_w3 = (const float*)d_in[16];
  const float* hm_b3 = (const float*)d_in[17];
  const float* hm_w4 = (const float*)d_in[18];
  const float* hm_b4 = (const float*)d_in[19];
  float* out = (float*)d_out;

  char* ws = (char*)d_ws;
  // weights: [2][N][Kp] split planes
  us* wPE1 = (us*)(ws + 0);         // 2*256*64   = 65536 B
  us* wPE2 = (us*)(ws + 65536);     // 2*128*256  = 131072 B
  us* wH1  = (us*)(ws + 196608);    // 2*1024*512 = 2097152 B
  us* wH2  = (us*)(ws + 2293760);   // 2*1024*1024= 4194304 B
  us* wH3  = (us*)(ws + 6488064);   // 4194304 B
  us* wH4  = (us*)(ws + 10682368);  // 2*128*1024 = 524288 B -> end 11206656

  // activations (liveness-aliased, peak 175.9 MB)
  float* posE = (float*)(ws + 11534336);   // [80000][128] f32, end 52.49M
  us*    hpe  = (us*)(ws + 53000192);      // [2][80000][256], end 134.92M
  us*    pein = (us*)(ws + 135000064);     // [2][80000][64],  end 155.48M
  us*    X0   = (us*)(ws + 53000192);      // [2][20000][512]  (hpe dead), end 93.96M
  us*    H1   = (us*)(ws + 94000128);      // [2][20000][1024], end 175.92M
  us*    H2   = (us*)(ws + 11534336);      // (posE/X0 dead), end 93.45M
  us*    H3   = (us*)(ws + 94000128);      // (H1 dead), end 175.92M

  // 0. weight transpose+split
  wsplit_kernel<<<dim3(8, 2),   256, 0, stream>>>(pe_w1, wPE1, 60,   256,  64);
  wsplit_kernel<<<dim3(4, 8),   256, 0, stream>>>(pe_w2, wPE2, 256,  128,  256);
  wsplit_kernel<<<dim3(32, 16), 256, 0, stream>>>(hm_w1, wH1,  512,  1024, 512);
  wsplit_kernel<<<dim3(32, 32), 256, 0, stream>>>(hm_w2, wH2,  1024, 1024, 1024);
  wsplit_kernel<<<dim3(32, 32), 256, 0, stream>>>(hm_w3, wH3,  1024, 1024, 1024);
  wsplit_kernel<<<dim3(4, 32),  256, 0, stream>>>(hm_w4, wH4,  1024, 128,  1024);

  // 1. PE features (split planes, K padded 60->64)
  pe_in_kernel<<<(PN * 64 + 255) / 256, 256, 0, stream>>>(rp, pein);

  // 2. PE MLP: 64 -> 256 (relu) -> 128 (f32 posE)
  gemm_aug<true, 1><<<dim3(2, 625), 256, 0, stream>>>(pein, wPE1, pe_b1, nullptr, hpe, PN, 256, 64);
  gemm_aug<false, 0><<<dim3(1, 625), 256, 0, stream>>>(hpe, wPE2, pe_b2, posE, nullptr, PN, 128, 256);

  // 3. fused softmax + projection + sampling -> X0 split planes
  sample_kernel<<<PN / 4, 256, 0, stream>>>(feat0, feat1, feat2, feat3, rp, l2i,
                                            wt_w, wt_b, posE, X0);

  // 4. head MLP: 512 -> 1024 -> 1024 -> 1024 -> 128
  gemm_aug<true, 1><<<dim3(8, 157), 256, 0, stream>>>(X0, wH1, hm_b1, nullptr, H1, QN, 1024, 512);
  gemm_aug<true, 1><<<dim3(8, 157), 256, 0, stream>>>(H1, wH2, hm_b2, nullptr, H2, QN, 1024, 1024);
  gemm_aug<true, 1><<<dim3(8, 157), 256, 0, stream>>>(H2, wH3, hm_b3, nullptr, H3, QN, 1024, 1024);
  gemm_aug<false, 0><<<dim3(1, 157), 256, 0, stream>>>(H3, wH4, hm_b4, out, nullptr, QN, 128, 1024);
}

// Round 7
// 621.614 us; speedup vs baseline: 1.2550x; 1.2550x over previous
//
#include <hip/hip_runtime.h>
#include <math.h>

#define QN 20000
#define PN 80000   // QN*4
#define CN 128
#define NVIEW 6

typedef __attribute__((ext_vector_type(8))) short bf16x8;
typedef __attribute__((ext_vector_type(4))) float f32x4;
typedef unsigned short us;

__device__ __forceinline__ us f2bf(float f) {
  unsigned u = __float_as_uint(f);
  return (us)((u + 0x7fffu + ((u >> 16) & 1u)) >> 16);
}
__device__ __forceinline__ float bf2f(us h) {
  return __uint_as_float(((unsigned)h) << 16);
}

__device__ __forceinline__ void gload16(const void* g, void* l) {
  __builtin_amdgcn_global_load_lds(
      (const __attribute__((address_space(1))) void*)g,
      (__attribute__((address_space(3))) void*)l, 16, 0, 0);
}

// ---------------- weight transpose+split: W[K][N] f32 -> T[2][N][Kp] bf16 ----
__global__ __launch_bounds__(256) void wsplit_kernel(const float* __restrict__ W,
                                                     us* __restrict__ Th,
                                                     int K, int N, int Kp) {
  __shared__ float t[32][33];
  us* Tl = Th + (size_t)N * Kp;
  const int n0 = blockIdx.x * 32, k0 = blockIdx.y * 32;
  const int tx = threadIdx.x & 31, ty = threadIdx.x >> 5;  // ty 0..7
  #pragma unroll
  for (int j = 0; j < 4; ++j) {
    int k = k0 + ty + j * 8;
    t[ty + j * 8][tx] = (k < K) ? W[(size_t)k * N + n0 + tx] : 0.f;
  }
  __syncthreads();
  #pragma unroll
  for (int j = 0; j < 4; ++j) {
    int n = n0 + ty + j * 8;
    int k = k0 + tx;
    float v = t[tx][ty + j * 8];
    us h = f2bf(v);
    Th[(size_t)n * Kp + k] = h;
    Tl[(size_t)n * Kp + k] = f2bf(v - bf2f(h));
  }
}

// ---------------- PE input features -> split bf16 planes [2][PN][64] ---------
__global__ __launch_bounds__(256) void pe_in_kernel(const float* __restrict__ rp,
                                                    us* __restrict__ Ph) {
  int idx = blockIdx.x * 256 + threadIdx.x;
  if (idx >= PN * 64) return;
  us* Pl = Ph + (size_t)PN * 64;
  int p = idx >> 6, k = idx & 63;
  float val = 0.f;
  if (k < 60) {
    int q = p >> 2, z = p & 3;
    int d = k / 20, r = k - d * 20;
    int j = (r >= 10) ? (r - 10) : r;
    float pos = rp[((size_t)z * QN + q) * 3 + d];
    float ang = pos * ((float)(1 << j) * 3.14159265358979323846f);
    val = (r >= 10) ? cosf(ang) : sinf(ang);
  }
  us h = f2bf(val);
  Ph[idx] = h;
  Pl[idx] = f2bf(val - bf2f(h));
}

// ---------------- split-bf16 3-term GEMM, single-pass 4-plane staging --------
// C = (Ah+Al)@(Bh+Bl)^T + bias, terms hh+lh+hl (al*bl ~2^-17 dropped).
// 128x128 tile, BK=32, 256 thr (2x2 waves, 64x64/wave). Per K-tile stage all
// 4 planes (32KB) double-buffered (64KB LDS, 2 blocks/CU); 48 MFMA/tile/wave.
// 2-phase pipeline: STAGE(t+1) issued before COMPUTE(t), one __syncthreads
// per tile (proven-safe full drain). XCD-aware bijective block swizzle so the
// N/128 column-blocks of one row-strip share the A-tile in one XCD's L2.
// LDS anti-conflict: slot ^= (row>>1)&3 (involution on source & read).
// OUT=0: f32 C. OUT=1: split bf16 planes (Cl = Ch + M*N).
template <bool RELU, int OUT>
__global__ __launch_bounds__(256, 2) void gemm3s(const us* __restrict__ Ah,
                                                 const us* __restrict__ Bh,
                                                 const float* __restrict__ bias,
                                                 float* __restrict__ Cf,
                                                 us* __restrict__ Ch,
                                                 int M, int N, int K, int nbn) {
  __shared__ short sm[2][4][4096];  // [buf][Ah,Al,Bh,Bl][128 rows * 32 k]
  const us* __restrict__ Al = Ah + (size_t)M * K;
  const us* __restrict__ Bl = Bh + (size_t)N * K;
  const int tid = threadIdx.x;
  const int wave = tid >> 6, lane = tid & 63;
  const int wr = wave >> 1, wc = wave & 1;
  const int g = lane >> 4, r16 = lane & 15;

  // bijective XCD swizzle (m204): XCD k gets a contiguous chunk of logical ids
  const int nwg = gridDim.x;
  const int q8 = nwg >> 3, r8 = nwg & 7;
  const int xcd = blockIdx.x & 7, sub = blockIdx.x >> 3;
  const int wg = (xcd < r8 ? xcd * (q8 + 1) : r8 * (q8 + 1) + (xcd - r8) * q8) + sub;
  const int bn = (wg % nbn) * 128;
  const int bm = (wg / nbn) * 128;

  const int nt = K >> 5;  // K/32 tiles

  f32x4 acc[4][4];
  #pragma unroll
  for (int i = 0; i < 4; ++i)
    #pragma unroll
    for (int j = 0; j < 4; ++j) acc[i][j] = {0.f, 0.f, 0.f, 0.f};

  // stage one K-tile: 4 planes x 128 rows x 32 k (8KB/plane), 8 instr/wave
  auto STAGE = [&](int buf, int t) {
    const int kof = t << 5;
    const int rsub = lane >> 2;                    // 0..15 row within group
    const int slot0 = lane & 3;                    // 16B slot within row
    #pragma unroll
    for (int pl = 0; pl < 4; ++pl) {
      const us* P = (pl == 0) ? Ah : (pl == 1) ? Al : (pl == 2) ? Bh : Bl;
      const int rbase = (pl < 2) ? bm : bn;
      #pragma unroll
      for (int i = 0; i < 2; ++i) {
        int group = wave * 2 + i;                  // 0..7 (16 rows each)
        int row = group * 16 + rsub;               // 0..127
        int slot = slot0 ^ ((row >> 1) & 3);       // pre-swizzled source
        int gr = rbase + row;
        if (pl < 2 && gr >= M) gr = M - 1;
        gload16(P + (size_t)gr * K + kof + slot * 8,
                &sm[buf][pl][group * 512]);        // linear LDS dest
      }
    }
  };

  auto COMPUTE = [&](int buf) {
    bf16x8 ah[4], al[4], bh[4], bl[4];
    #pragma unroll
    for (int mi = 0; mi < 4; ++mi) {
      int row = wr * 64 + mi * 16 + r16;
      int off = row * 32 + ((g ^ ((row >> 1) & 3)) * 8);  // swizzled read
      ah[mi] = *(const bf16x8*)&sm[buf][0][off];
      al[mi] = *(const bf16x8*)&sm[buf][1][off];
    }
    #pragma unroll
    for (int ni = 0; ni < 4; ++ni) {
      int row = wc * 64 + ni * 16 + r16;
      int off = row * 32 + ((g ^ ((row >> 1) & 3)) * 8);
      bh[ni] = *(const bf16x8*)&sm[buf][2][off];
      bl[ni] = *(const bf16x8*)&sm[buf][3][off];
    }
    #pragma unroll
    for (int mi = 0; mi < 4; ++mi)
      #pragma unroll
      for (int ni = 0; ni < 4; ++ni)
        acc[mi][ni] = __builtin_amdgcn_mfma_f32_16x16x32_bf16(ah[mi], bh[ni], acc[mi][ni], 0, 0, 0);
    #pragma unroll
    for (int mi = 0; mi < 4; ++mi)
      #pragma unroll
      for (int ni = 0; ni < 4; ++ni)
        acc[mi][ni] = __builtin_amdgcn_mfma_f32_16x16x32_bf16(al[mi], bh[ni], acc[mi][ni], 0, 0, 0);
    #pragma unroll
    for (int mi = 0; mi < 4; ++mi)
      #pragma unroll
      for (int ni = 0; ni < 4; ++ni)
        acc[mi][ni] = __builtin_amdgcn_mfma_f32_16x16x32_bf16(ah[mi], bl[ni], acc[mi][ni], 0, 0, 0);
  };

  STAGE(0, 0);
  __syncthreads();                 // vmcnt(0)+lgkmcnt(0)+barrier

  for (int t = 0; t < nt; ++t) {
    if (t + 1 < nt) STAGE((t + 1) & 1, t + 1);  // prefetch next (issue only)
    COMPUTE(t & 1);                             // 48 MFMA overlap the loads
    __syncthreads();               // drain prefetch + WAR fence, once per tile
  }

  // epilogue: D row = (lane>>4)*4 + r, col = lane&15 within each 16x16 frag
  us* Cl = Ch + (size_t)M * N;
  #pragma unroll
  for (int mi = 0; mi < 4; ++mi) {
    int gr0 = bm + wr * 64 + mi * 16 + (lane >> 4) * 4;
    #pragma unroll
    for (int ni = 0; ni < 4; ++ni) {
      int gc = bn + wc * 64 + ni * 16 + r16;
      float bv = bias[gc];
      #pragma unroll
      for (int r = 0; r < 4; ++r) {
        int row = gr0 + r;
        if (row >= M) continue;
        float v = acc[mi][ni][r] + bv;
        if (RELU) v = fmaxf(v, 0.f);
        if (OUT == 0) {
          Cf[(size_t)row * N + gc] = v;
        } else {
          us h = f2bf(v);
          Ch[(size_t)row * N + gc] = h;
          Cl[(size_t)row * N + gc] = f2bf(v - bf2f(h));
        }
      }
    }
  }
}

// ---------------- fused softmax + projection + bilinear sample --------------
// one wave per point; lane handles channels [2*lane, 2*lane+2) as float2.
__global__ __launch_bounds__(256) void sample_kernel(
    const float* __restrict__ f0, const float* __restrict__ f1,
    const float* __restrict__ f2, const float* __restrict__ f3,
    const float* __restrict__ rp, const float* __restrict__ l2i,
    const float* __restrict__ wtw, const float* __restrict__ wtb,
    const float* __restrict__ posE, us* __restrict__ X0h) {
  __shared__ float sl2i[96];
  __shared__ float swtT[512];  // transposed [4][128]
  __shared__ float sb[4];
  const int tid = threadIdx.x;
  if (tid < 96) sl2i[tid] = l2i[tid];
  for (int i = tid; i < 512; i += 256) swtT[(i & 3) * 128 + (i >> 2)] = wtw[i];
  if (tid < 4) sb[tid] = wtb[tid];
  __syncthreads();

  us* X0l = X0h + (size_t)QN * 512;
  const int wave = tid >> 6, lane = tid & 63;
  const int p = blockIdx.x * 4 + wave;
  const int q = p >> 2, z = p & 3;

  const float X  = rp[((size_t)z * QN + q) * 3 + 0] * 100.f - 50.f;
  const float Y  = rp[((size_t)z * QN + q) * 3 + 1] * 100.f - 50.f;
  const float Zc = rp[((size_t)z * QN + q) * 3 + 2] * 8.f - 4.f;

  const int c0 = lane * 2;
  float2 pe = *(const float2*)(posE + (size_t)p * CN + c0);
  const float e0 = pe.x, e1 = pe.y;

  float l0 = e0 * swtT[0 * 128 + c0] + e1 * swtT[0 * 128 + c0 + 1];
  float l1 = e0 * swtT[1 * 128 + c0] + e1 * swtT[1 * 128 + c0 + 1];
  float l2 = e0 * swtT[2 * 128 + c0] + e1 * swtT[2 * 128 + c0 + 1];
  float l3 = e0 * swtT[3 * 128 + c0] + e1 * swtT[3 * 128 + c0 + 1];
  #pragma unroll
  for (int off = 32; off > 0; off >>= 1) {
    l0 += __shfl_xor(l0, off);
    l1 += __shfl_xor(l1, off);
    l2 += __shfl_xor(l2, off);
    l3 += __shfl_xor(l3, off);
  }
  l0 += sb[0]; l1 += sb[1]; l2 += sb[2]; l3 += sb[3];
  float mx = fmaxf(fmaxf(l0, l1), fmaxf(l2, l3));
  float ex0 = __expf(l0 - mx), ex1 = __expf(l1 - mx);
  float ex2 = __expf(l2 - mx), ex3 = __expf(l3 - mx);
  float esr = 1.f / (ex0 + ex1 + ex2 + ex3);
  float sw[4] = {ex0 * esr, ex1 * esr, ex2 * esr, ex3 * esr};

  const int HH[4] = {64, 32, 16, 8};
  const int WW[4] = {176, 88, 44, 22};
  const float* FT[4] = {f0, f1, f2, f3};

  float acc0 = 0.f, acc1 = 0.f;
  for (int n = 0; n < NVIEW; n++) {
    const float* Mx = sl2i + n * 16;
    float cam0 = Mx[0] * X + Mx[1] * Y + Mx[2]  * Zc + Mx[3];
    float cam1 = Mx[4] * X + Mx[5] * Y + Mx[6]  * Zc + Mx[7];
    float cam2 = Mx[8] * X + Mx[9] * Y + Mx[10] * Zc + Mx[11];
    float denom = fmaxf(cam2, 1e-5f);
    float u = cam0 / denom * (1.f / 704.f);
    float v = cam1 / denom * (1.f / 256.f);
    if (!(cam2 > 1e-5f && u > 0.f && u < 1.f && v > 0.f && v < 1.f)) continue;
    #pragma unroll
    for (int l = 0; l < 4; l++) {
      const int Hl = HH[l], Wl = WW[l];
      float pxl = u * (float)Wl - 0.5f;
      float pyl = v * (float)Hl - 0.5f;
      float fx = floorf(pxl), fy = floorf(pyl);
      int x0 = (int)fx, y0 = (int)fy;
      float wx = pxl - fx, wy = pyl - fy;
      const float wxs[2] = {1.f - wx, wx};
      const float wys[2] = {1.f - wy, wy};
      const float* fb = FT[l] + (size_t)n * Hl * Wl * CN;
      #pragma unroll
      for (int cy = 0; cy < 2; cy++) {
        #pragma unroll
        for (int cx = 0; cx < 2; cx++) {
          int xi = x0 + cx, yi = y0 + cy;
          bool inb = (xi >= 0) & (xi < Wl) & (yi >= 0) & (yi < Hl);
          int xc = min(max(xi, 0), Wl - 1);
          int yc = min(max(yi, 0), Hl - 1);
          float wgt = inb ? (wys[cy] * wxs[cx] * sw[l]) : 0.f;
          float2 vv = ((const float2*)(fb + ((size_t)yc * Wl + xc) * CN))[lane];
          acc0 = fmaf(wgt, vv.x, acc0);
          acc1 = fmaf(wgt, vv.y, acc1);
        }
      }
    }
  }
  float v0 = acc0 + e0;
  float v1 = acc1 + e1;
  size_t base = (size_t)p * CN + c0;  // = q*512 + z*128 + c0
  us h0 = f2bf(v0), h1 = f2bf(v1);
  ushort2 hi = {h0, h1};
  ushort2 lo = {f2bf(v0 - bf2f(h0)), f2bf(v1 - bf2f(h1))};
  *(ushort2*)&X0h[base] = hi;
  *(ushort2*)&X0l[base] = lo;
}

extern "C" void kernel_launch(void* const* d_in, const int* in_sizes, int n_in,
                              void* d_out, int out_size, void* d_ws, size_t ws_size,
                              hipStream_t stream) {
  const float* feat0 = (const float*)d_in[0];
  const float* feat1 = (const float*)d_in[1];
  const float* feat2 = (const float*)d_in[2];
  const float* feat3 = (const float*)d_in[3];
  const float* rp    = (const float*)d_in[4];
  const float* l2i   = (const float*)d_in[5];
  const float* pe_w1 = (const float*)d_in[6];
  const float* pe_b1 = (const float*)d_in[7];
  const float* pe_w2 = (const float*)d_in[8];
  const float* pe_b2 = (const float*)d_in[9];
  const float* wt_w  = (const float*)d_in[10];
  const float* wt_b  = (const float*)d_in[11];
  const float* hm_w1 = (const float*)d_in[12];
  const float* hm_b1 = (const float*)d_in[13];
  const float* hm_w2 = (const float*)d_in[14];
  const float* hm_b2 = (const float*)d_in[15];
  const float* hm_w3 = (const float*)d_in[16];
  const float* hm_b3 = (const float*)d_in[17];
  const float* hm_w4 = (const float*)d_in[18];
  const float* hm_b4 = (const float*)d_in[19];
  float* out = (float*)d_out;

  char* ws = (char*)d_ws;
  // weights: [2][N][Kp] split planes
  us* wPE1 = (us*)(ws + 0);         // 2*256*64   = 65536 B
  us* wPE2 = (us*)(ws + 65536);     // 2*128*256  = 131072 B
  us* wH1  = (us*)(ws + 196608);    // 2*1024*512 = 2097152 B
  us* wH2  = (us*)(ws + 2293760);   // 2*1024*1024= 4194304 B
  us* wH3  = (us*)(ws + 6488064);   // 4194304 B
  us* wH4  = (us*)(ws + 10682368);  // 2*128*1024 = 524288 B -> end 11206656

  // activations (liveness-aliased, peak 175.9 MB)
  float* posE = (float*)(ws + 11534336);   // [80000][128] f32, end 52.49M
  us*    hpe  = (us*)(ws + 53000192);      // [2][80000][256], end 134.92M
  us*    pein = (us*)(ws + 135000064);     // [2][80000][64],  end 155.48M
  us*    X0   = (us*)(ws + 53000192);      // [2][20000][512]  (hpe dead), end 93.96M
  us*    H1   = (us*)(ws + 94000128);      // [2][20000][1024], end 175.92M
  us*    H2   = (us*)(ws + 11534336);      // (posE/X0 dead), end 93.45M
  us*    H3   = (us*)(ws + 94000128);      // (H1 dead), end 175.92M

  // 0. weight transpose+split
  wsplit_kernel<<<dim3(8, 2),   256, 0, stream>>>(pe_w1, wPE1, 60,   256,  64);
  wsplit_kernel<<<dim3(4, 8),   256, 0, stream>>>(pe_w2, wPE2, 256,  128,  256);
  wsplit_kernel<<<dim3(32, 16), 256, 0, stream>>>(hm_w1, wH1,  512,  1024, 512);
  wsplit_kernel<<<dim3(32, 32), 256, 0, stream>>>(hm_w2, wH2,  1024, 1024, 1024);
  wsplit_kernel<<<dim3(32, 32), 256, 0, stream>>>(hm_w3, wH3,  1024, 1024, 1024);
  wsplit_kernel<<<dim3(4, 32),  256, 0, stream>>>(hm_w4, wH4,  1024, 128,  1024);

  // 1. PE features (split planes, K padded 60->64)
  pe_in_kernel<<<(PN * 64 + 255) / 256, 256, 0, stream>>>(rp, pein);

  // 2. PE MLP: 64 -> 256 (relu) -> 128 (f32 posE)
  gemm3s<true, 1><<<2 * 625, 256, 0, stream>>>(pein, wPE1, pe_b1, nullptr, hpe, PN, 256, 64, 2);
  gemm3s<false, 0><<<1 * 625, 256, 0, stream>>>(hpe, wPE2, pe_b2, posE, nullptr, PN, 128, 256, 1);

  // 3. fused softmax + projection + sampling -> X0 split planes
  sample_kernel<<<PN / 4, 256, 0, stream>>>(feat0, feat1, feat2, feat3, rp, l2i,
                                            wt_w, wt_b, posE, X0);

  // 4. head MLP: 512 -> 1024 -> 1024 -> 1024 -> 128
  gemm3s<true, 1><<<8 * 157, 256, 0, stream>>>(X0, wH1, hm_b1, nullptr, H1, QN, 1024, 512, 8);
  gemm3s<true, 1><<<8 * 157, 256, 0, stream>>>(H1, wH2, hm_b2, nullptr, H2, QN, 1024, 1024, 8);
  gemm3s<true, 1><<<8 * 157, 256, 0, stream>>>(H2, wH3, hm_b3, nullptr, H3, QN, 1024, 1024, 8);
  gemm3s<false, 0><<<1 * 157, 256, 0, stream>>>(H3, wH4, hm_b4, out, nullptr, QN, 128, 1024, 1);
}

// Round 8
// 566.559 us; speedup vs baseline: 1.3769x; 1.0972x over previous
//
#include <hip/hip_runtime.h>
#include <math.h>

#define QN 20000
#define PN 80000   // QN*4
#define CN 128
#define NVIEW 6

typedef __attribute__((ext_vector_type(8))) short bf16x8;
typedef __attribute__((ext_vector_type(4))) float f32x4;
typedef __attribute__((ext_vector_type(4))) unsigned short us4;
typedef unsigned short us;

__device__ __forceinline__ us f2bf(float f) {
  unsigned u = __float_as_uint(f);
  return (us)((u + 0x7fffu + ((u >> 16) & 1u)) >> 16);
}
__device__ __forceinline__ float bf2f(us h) {
  return __uint_as_float(((unsigned)h) << 16);
}

__device__ __forceinline__ void gload16(const void* g, void* l) {
  __builtin_amdgcn_global_load_lds(
      (const __attribute__((address_space(1))) void*)g,
      (__attribute__((address_space(3))) void*)l, 16, 0, 0);
}

// ---------------- weight transpose+split: W[K][N] f32 -> T[2][N][Kp] bf16 ----
__global__ __launch_bounds__(256) void wsplit_kernel(const float* __restrict__ W,
                                                     us* __restrict__ Th,
                                                     int K, int N, int Kp) {
  __shared__ float t[32][33];
  us* Tl = Th + (size_t)N * Kp;
  const int n0 = blockIdx.x * 32, k0 = blockIdx.y * 32;
  const int tx = threadIdx.x & 31, ty = threadIdx.x >> 5;  // ty 0..7
  #pragma unroll
  for (int j = 0; j < 4; ++j) {
    int k = k0 + ty + j * 8;
    t[ty + j * 8][tx] = (k < K) ? W[(size_t)k * N + n0 + tx] : 0.f;
  }
  __syncthreads();
  #pragma unroll
  for (int j = 0; j < 4; ++j) {
    int n = n0 + ty + j * 8;
    int k = k0 + tx;
    float v = t[tx][ty + j * 8];
    us h = f2bf(v);
    Th[(size_t)n * Kp + k] = h;
    Tl[(size_t)n * Kp + k] = f2bf(v - bf2f(h));
  }
}

// ---------------- PE input features -> split bf16 planes [2][PN][64] ---------
__global__ __launch_bounds__(256) void pe_in_kernel(const float* __restrict__ rp,
                                                    us* __restrict__ Ph) {
  int idx = blockIdx.x * 256 + threadIdx.x;
  if (idx >= PN * 64) return;
  us* Pl = Ph + (size_t)PN * 64;
  int p = idx >> 6, k = idx & 63;
  float val = 0.f;
  if (k < 60) {
    int q = p >> 2, z = p & 3;
    int d = k / 20, r = k - d * 20;
    int j = (r >= 10) ? (r - 10) : r;
    float pos = rp[((size_t)z * QN + q) * 3 + d];
    float ang = pos * ((float)(1 << j) * 3.14159265358979323846f);
    val = (r >= 10) ? cosf(ang) : sinf(ang);
  }
  us h = f2bf(val);
  Ph[idx] = h;
  Pl[idx] = f2bf(val - bf2f(h));
}

// ---------------- split-bf16 3-term GEMM, single-pass 4-plane staging --------
// (unchanged from round 7 -- verified: 0 bank conflicts, single-pass fetch)
template <bool RELU, int OUT>
__global__ __launch_bounds__(256, 2) void gemm3s(const us* __restrict__ Ah,
                                                 const us* __restrict__ Bh,
                                                 const float* __restrict__ bias,
                                                 float* __restrict__ Cf,
                                                 us* __restrict__ Ch,
                                                 int M, int N, int K, int nbn) {
  __shared__ short sm[2][4][4096];  // [buf][Ah,Al,Bh,Bl][128 rows * 32 k]
  const us* __restrict__ Al = Ah + (size_t)M * K;
  const us* __restrict__ Bl = Bh + (size_t)N * K;
  const int tid = threadIdx.x;
  const int wave = tid >> 6, lane = tid & 63;
  const int wr = wave >> 1, wc = wave & 1;
  const int g = lane >> 4, r16 = lane & 15;

  // bijective XCD swizzle (m204)
  const int nwg = gridDim.x;
  const int q8 = nwg >> 3, r8 = nwg & 7;
  const int xcd = blockIdx.x & 7, sub = blockIdx.x >> 3;
  const int wg = (xcd < r8 ? xcd * (q8 + 1) : r8 * (q8 + 1) + (xcd - r8) * q8) + sub;
  const int bn = (wg % nbn) * 128;
  const int bm = (wg / nbn) * 128;

  const int nt = K >> 5;  // K/32 tiles

  f32x4 acc[4][4];
  #pragma unroll
  for (int i = 0; i < 4; ++i)
    #pragma unroll
    for (int j = 0; j < 4; ++j) acc[i][j] = {0.f, 0.f, 0.f, 0.f};

  auto STAGE = [&](int buf, int t) {
    const int kof = t << 5;
    const int rsub = lane >> 2;
    const int slot0 = lane & 3;
    #pragma unroll
    for (int pl = 0; pl < 4; ++pl) {
      const us* P = (pl == 0) ? Ah : (pl == 1) ? Al : (pl == 2) ? Bh : Bl;
      const int rbase = (pl < 2) ? bm : bn;
      #pragma unroll
      for (int i = 0; i < 2; ++i) {
        int group = wave * 2 + i;
        int row = group * 16 + rsub;
        int slot = slot0 ^ ((row >> 1) & 3);
        int gr = rbase + row;
        if (pl < 2 && gr >= M) gr = M - 1;
        gload16(P + (size_t)gr * K + kof + slot * 8,
                &sm[buf][pl][group * 512]);
      }
    }
  };

  auto COMPUTE = [&](int buf) {
    bf16x8 ah[4], al[4], bh[4], bl[4];
    #pragma unroll
    for (int mi = 0; mi < 4; ++mi) {
      int row = wr * 64 + mi * 16 + r16;
      int off = row * 32 + ((g ^ ((row >> 1) & 3)) * 8);
      ah[mi] = *(const bf16x8*)&sm[buf][0][off];
      al[mi] = *(const bf16x8*)&sm[buf][1][off];
    }
    #pragma unroll
    for (int ni = 0; ni < 4; ++ni) {
      int row = wc * 64 + ni * 16 + r16;
      int off = row * 32 + ((g ^ ((row >> 1) & 3)) * 8);
      bh[ni] = *(const bf16x8*)&sm[buf][2][off];
      bl[ni] = *(const bf16x8*)&sm[buf][3][off];
    }
    #pragma unroll
    for (int mi = 0; mi < 4; ++mi)
      #pragma unroll
      for (int ni = 0; ni < 4; ++ni)
        acc[mi][ni] = __builtin_amdgcn_mfma_f32_16x16x32_bf16(ah[mi], bh[ni], acc[mi][ni], 0, 0, 0);
    #pragma unroll
    for (int mi = 0; mi < 4; ++mi)
      #pragma unroll
      for (int ni = 0; ni < 4; ++ni)
        acc[mi][ni] = __builtin_amdgcn_mfma_f32_16x16x32_bf16(al[mi], bh[ni], acc[mi][ni], 0, 0, 0);
    #pragma unroll
    for (int mi = 0; mi < 4; ++mi)
      #pragma unroll
      for (int ni = 0; ni < 4; ++ni)
        acc[mi][ni] = __builtin_amdgcn_mfma_f32_16x16x32_bf16(ah[mi], bl[ni], acc[mi][ni], 0, 0, 0);
  };

  STAGE(0, 0);
  __syncthreads();

  for (int t = 0; t < nt; ++t) {
    if (t + 1 < nt) STAGE((t + 1) & 1, t + 1);
    COMPUTE(t & 1);
    __syncthreads();
  }

  us* Cl = Ch + (size_t)M * N;
  #pragma unroll
  for (int mi = 0; mi < 4; ++mi) {
    int gr0 = bm + wr * 64 + mi * 16 + (lane >> 4) * 4;
    #pragma unroll
    for (int ni = 0; ni < 4; ++ni) {
      int gc = bn + wc * 64 + ni * 16 + r16;
      float bv = bias[gc];
      #pragma unroll
      for (int r = 0; r < 4; ++r) {
        int row = gr0 + r;
        if (row >= M) continue;
        float v = acc[mi][ni][r] + bv;
        if (RELU) v = fmaxf(v, 0.f);
        if (OUT == 0) {
          Cf[(size_t)row * N + gc] = v;
        } else {
          us h = f2bf(v);
          Ch[(size_t)row * N + gc] = h;
          Cl[(size_t)row * N + gc] = f2bf(v - bf2f(h));
        }
      }
    }
  }
}

// ---------------- fused softmax + projection + bilinear sample --------------
// 2 points per wave: lanes [0,32) = point A, [32,64) = point B. Each 32-lane
// half covers 128 channels via float4 (16B/lane). Per-corner scalar math
// serves both points per wave-instruction (2x less VALU/point vs 1-pt/wave).
__global__ __launch_bounds__(256) void sample_kernel(
    const float* __restrict__ f0, const float* __restrict__ f1,
    const float* __restrict__ f2, const float* __restrict__ f3,
    const float* __restrict__ rp, const float* __restrict__ l2i,
    const float* __restrict__ wtw, const float* __restrict__ wtb,
    const float* __restrict__ posE, us* __restrict__ X0h) {
  __shared__ float sl2i[96];
  __shared__ float swtT[512];  // transposed [4][128]
  __shared__ float sb[4];
  const int tid = threadIdx.x;
  if (tid < 96) sl2i[tid] = l2i[tid];
  for (int i = tid; i < 512; i += 256) swtT[(i & 3) * 128 + (i >> 2)] = wtw[i];
  if (tid < 4) sb[tid] = wtb[tid];
  __syncthreads();

  us* X0l = X0h + (size_t)QN * 512;
  const int wave = tid >> 6, lane = tid & 63;
  const int half = lane >> 5, s = lane & 31;
  const int p = blockIdx.x * 8 + wave * 2 + half;
  const int q = p >> 2, z = p & 3;

  const float X  = rp[((size_t)z * QN + q) * 3 + 0] * 100.f - 50.f;
  const float Y  = rp[((size_t)z * QN + q) * 3 + 1] * 100.f - 50.f;
  const float Zc = rp[((size_t)z * QN + q) * 3 + 2] * 8.f - 4.f;

  const int c0 = s * 4;
  f32x4 pe = *(const f32x4*)(posE + (size_t)p * CN + c0);

  // level-weight logits over this half's 128 channels
  float l0 = pe[0] * swtT[0 * 128 + c0] + pe[1] * swtT[0 * 128 + c0 + 1]
           + pe[2] * swtT[0 * 128 + c0 + 2] + pe[3] * swtT[0 * 128 + c0 + 3];
  float l1 = pe[0] * swtT[1 * 128 + c0] + pe[1] * swtT[1 * 128 + c0 + 1]
           + pe[2] * swtT[1 * 128 + c0 + 2] + pe[3] * swtT[1 * 128 + c0 + 3];
  float l2 = pe[0] * swtT[2 * 128 + c0] + pe[1] * swtT[2 * 128 + c0 + 1]
           + pe[2] * swtT[2 * 128 + c0 + 2] + pe[3] * swtT[2 * 128 + c0 + 3];
  float l3 = pe[0] * swtT[3 * 128 + c0] + pe[1] * swtT[3 * 128 + c0 + 1]
           + pe[2] * swtT[3 * 128 + c0 + 2] + pe[3] * swtT[3 * 128 + c0 + 3];
  #pragma unroll
  for (int off = 16; off > 0; off >>= 1) {  // within-half butterfly
    l0 += __shfl_xor(l0, off);
    l1 += __shfl_xor(l1, off);
    l2 += __shfl_xor(l2, off);
    l3 += __shfl_xor(l3, off);
  }
  l0 += sb[0]; l1 += sb[1]; l2 += sb[2]; l3 += sb[3];
  float mx = fmaxf(fmaxf(l0, l1), fmaxf(l2, l3));
  float ex0 = __expf(l0 - mx), ex1 = __expf(l1 - mx);
  float ex2 = __expf(l2 - mx), ex3 = __expf(l3 - mx);
  float esr = 1.f / (ex0 + ex1 + ex2 + ex3);
  float swl[4] = {ex0 * esr, ex1 * esr, ex2 * esr, ex3 * esr};

  const float* FT[4] = {f0, f1, f2, f3};

  float a0 = 0.f, a1 = 0.f, a2 = 0.f, a3 = 0.f;
  for (int n = 0; n < NVIEW; n++) {
    const float* Mx = sl2i + n * 16;
    float cam0 = Mx[0] * X + Mx[1] * Y + Mx[2]  * Zc + Mx[3];
    float cam1 = Mx[4] * X + Mx[5] * Y + Mx[6]  * Zc + Mx[7];
    float cam2 = Mx[8] * X + Mx[9] * Y + Mx[10] * Zc + Mx[11];
    float denom = fmaxf(cam2, 1e-5f);
    float u = cam0 / denom * (1.f / 704.f);
    float v = cam1 / denom * (1.f / 256.f);
    bool valid = (cam2 > 1e-5f) & (u > 0.f) & (u < 1.f) & (v > 0.f) & (v < 1.f);
    if (valid) {  // per-half divergent; execz-skips when both halves miss
      #pragma unroll
      for (int l = 0; l < 4; l++) {
        const int Hl = 64 >> l, Wl = 176 >> l;
        float pxl = u * (float)Wl - 0.5f;
        float pyl = v * (float)Hl - 0.5f;
        float fx = floorf(pxl), fy = floorf(pyl);
        int x0 = (int)fx, y0 = (int)fy;
        float wx = pxl - fx, wy = pyl - fy;
        const float wxs[2] = {1.f - wx, wx};
        const float wys[2] = {1.f - wy, wy};
        const float* fb = FT[l] + (size_t)n * (Hl * Wl * CN);
        #pragma unroll
        for (int cy = 0; cy < 2; cy++) {
          #pragma unroll
          for (int cx = 0; cx < 2; cx++) {
            int xi = x0 + cx, yi = y0 + cy;
            bool inb = ((unsigned)xi < (unsigned)Wl) & ((unsigned)yi < (unsigned)Hl);
            int off = inb ? (yi * Wl + xi) * CN : 0;          // cndmask addr
            float wgt = inb ? (wys[cy] * wxs[cx] * swl[l]) : 0.f;
            f32x4 vv = *(const f32x4*)(fb + off + c0);
            a0 = fmaf(wgt, vv[0], a0);
            a1 = fmaf(wgt, vv[1], a1);
            a2 = fmaf(wgt, vv[2], a2);
            a3 = fmaf(wgt, vv[3], a3);
          }
        }
      }
    }
  }
  float o0 = a0 + pe[0], o1 = a1 + pe[1], o2 = a2 + pe[2], o3 = a3 + pe[3];
  size_t base = (size_t)p * CN + c0;  // = q*512 + z*128 + c0
  us4 hi, lo;
  hi[0] = f2bf(o0); lo[0] = f2bf(o0 - bf2f(hi[0]));
  hi[1] = f2bf(o1); lo[1] = f2bf(o1 - bf2f(hi[1]));
  hi[2] = f2bf(o2); lo[2] = f2bf(o2 - bf2f(hi[2]));
  hi[3] = f2bf(o3); lo[3] = f2bf(o3 - bf2f(hi[3]));
  *(us4*)&X0h[base] = hi;
  *(us4*)&X0l[base] = lo;
}

extern "C" void kernel_launch(void* const* d_in, const int* in_sizes, int n_in,
                              void* d_out, int out_size, void* d_ws, size_t ws_size,
                              hipStream_t stream) {
  const float* feat0 = (const float*)d_in[0];
  const float* feat1 = (const float*)d_in[1];
  const float* feat2 = (const float*)d_in[2];
  const float* feat3 = (const float*)d_in[3];
  const float* rp    = (const float*)d_in[4];
  const float* l2i   = (const float*)d_in[5];
  const float* pe_w1 = (const float*)d_in[6];
  const float* pe_b1 = (const float*)d_in[7];
  const float* pe_w2 = (const float*)d_in[8];
  const float* pe_b2 = (const float*)d_in[9];
  const float* wt_w  = (const float*)d_in[10];
  const float* wt_b  = (const float*)d_in[11];
  const float* hm_w1 = (const float*)d_in[12];
  const float* hm_b1 = (const float*)d_in[13];
  const float* hm_w2 = (const float*)d_in[14];
  const float* hm_b2 = (const float*)d_in[15];
  const float* hm_w3 = (const float*)d_in[16];
  const float* hm_b3 = (const float*)d_in[17];
  const float* hm_w4 = (const float*)d_in[18];
  const float* hm_b4 = (const float*)d_in[19];
  float* out = (float*)d_out;

  char* ws = (char*)d_ws;
  // weights: [2][N][Kp] split planes
  us* wPE1 = (us*)(ws + 0);         // 2*256*64   = 65536 B
  us* wPE2 = (us*)(ws + 65536);     // 2*128*256  = 131072 B
  us* wH1  = (us*)(ws + 196608);    // 2*1024*512 = 2097152 B
  us* wH2  = (us*)(ws + 2293760);   // 2*1024*1024= 4194304 B
  us* wH3  = (us*)(ws + 6488064);   // 4194304 B
  us* wH4  = (us*)(ws + 10682368);  // 2*128*1024 = 524288 B -> end 11206656

  // activations (liveness-aliased, peak 175.9 MB)
  float* posE = (float*)(ws + 11534336);   // [80000][128] f32, end 52.49M
  us*    hpe  = (us*)(ws + 53000192);      // [2][80000][256], end 134.92M
  us*    pein = (us*)(ws + 135000064);     // [2][80000][64],  end 155.48M
  us*    X0   = (us*)(ws + 53000192);      // [2][20000][512]  (hpe dead), end 93.96M
  us*    H1   = (us*)(ws + 94000128);      // [2][20000][1024], end 175.92M
  us*    H2   = (us*)(ws + 11534336);      // (posE/X0 dead), end 93.45M
  us*    H3   = (us*)(ws + 94000128);      // (H1 dead), end 175.92M

  // 0. weight transpose+split
  wsplit_kernel<<<dim3(8, 2),   256, 0, stream>>>(pe_w1, wPE1, 60,   256,  64);
  wsplit_kernel<<<dim3(4, 8),   256, 0, stream>>>(pe_w2, wPE2, 256,  128,  256);
  wsplit_kernel<<<dim3(32, 16), 256, 0, stream>>>(hm_w1, wH1,  512,  1024, 512);
  wsplit_kernel<<<dim3(32, 32), 256, 0, stream>>>(hm_w2, wH2,  1024, 1024, 1024);
  wsplit_kernel<<<dim3(32, 32), 256, 0, stream>>>(hm_w3, wH3,  1024, 1024, 1024);
  wsplit_kernel<<<dim3(4, 32),  256, 0, stream>>>(hm_w4, wH4,  1024, 128,  1024);

  // 1. PE features (split planes, K padded 60->64)
  pe_in_kernel<<<(PN * 64 + 255) / 256, 256, 0, stream>>>(rp, pein);

  // 2. PE MLP: 64 -> 256 (relu) -> 128 (f32 posE)
  gemm3s<true, 1><<<2 * 625, 256, 0, stream>>>(pein, wPE1, pe_b1, nullptr, hpe, PN, 256, 64, 2);
  gemm3s<false, 0><<<1 * 625, 256, 0, stream>>>(hpe, wPE2, pe_b2, posE, nullptr, PN, 128, 256, 1);

  // 3. fused softmax + projection + sampling -> X0 split planes
  sample_kernel<<<PN / 8, 256, 0, stream>>>(feat0, feat1, feat2, feat3, rp, l2i,
                                            wt_w, wt_b, posE, X0);

  // 4. head MLP: 512 -> 1024 -> 1024 -> 1024 -> 128
  gemm3s<true, 1><<<8 * 157, 256, 0, stream>>>(X0, wH1, hm_b1, nullptr, H1, QN, 1024, 512, 8);
  gemm3s<true, 1><<<8 * 157, 256, 0, stream>>>(H1, wH2, hm_b2, nullptr, H2, QN, 1024, 1024, 8);
  gemm3s<true, 1><<<8 * 157, 256, 0, stream>>>(H2, wH3, hm_b3, nullptr, H3, QN, 1024, 1024, 8);
  gemm3s<false, 0><<<1 * 157, 256, 0, stream>>>(H3, wH4, hm_b4, out, nullptr, QN, 128, 1024, 1);
}